// Round 2
// baseline (307.176 us; speedup 1.0000x reference)
//
#include <hip/hip_runtime.h>
#include <hip/hip_bf16.h>

#define H 4
#define C 32
#define CQ 128
#define NSEQ 256
#define HC 128   // H*C

typedef __bf16 bf16;
typedef __bf16 bf16x8 __attribute__((ext_vector_type(8)));
typedef __bf16 bf16x4 __attribute__((ext_vector_type(4)));
typedef float f32x4 __attribute__((ext_vector_type(4)));

#define MFMA16(a, b, c) __builtin_amdgcn_mfma_f32_16x16x32_bf16(a, b, c, 0, 0, 0)

#define LOG2E 1.4426950408889634f

// ---------------------------------------------------------------------------
// Convert the 5 weight matrices (each 128x128 f32) to bf16 in ws.
// grid (16, 5) x 256 threads, each thread converts 4 elements.
// ---------------------------------------------------------------------------
__global__ __launch_bounds__(256) void prep_weights(const float* __restrict__ wq,
                                                    const float* __restrict__ wk,
                                                    const float* __restrict__ wv,
                                                    const float* __restrict__ wg,
                                                    const float* __restrict__ wo,
                                                    bf16* __restrict__ dst) {
    const int m = blockIdx.y;
    const float* src = (m == 0) ? wq : (m == 1) ? wk : (m == 2) ? wv : (m == 3) ? wg : wo;
    int i = blockIdx.x * 256 + threadIdx.x;  // 4096 float4's per matrix
    float4 v = ((const float4*)src)[i];
    bf16x4 b = {(bf16)v.x, (bf16)v.y, (bf16)v.z, (bf16)v.w};
    ((bf16x4*)(dst + (size_t)m * 16384))[i] = b;
}

// ---------------------------------------------------------------------------
// Dual projection, both input streams in one dispatch (blockIdx.y = mode).
// mode 0: q = (q_x @ w_q^T) * (1/sqrt(32) * log2e),  g = sigmoid(q_x @ w_g^T)
// mode 1: k = kv_x @ w_k^T,  v = kv_x @ w_v^T
// x-tile (64 rows) staged in LDS; weight fragments read from global bf16.
// ---------------------------------------------------------------------------
__global__ __launch_bounds__(256, 3) void proj_all(const float* __restrict__ qx,
                                                   const float* __restrict__ kvx,
                                                   const bf16* __restrict__ wbf,
                                                   bf16* __restrict__ qo,
                                                   bf16* __restrict__ go,
                                                   bf16* __restrict__ ko,
                                                   bf16* __restrict__ vo) {
    __shared__ bf16 xs[64][136];
    const int t = threadIdx.x;
    const int mode = blockIdx.y;
    const int m0 = blockIdx.x * 64;

    const float* x = mode ? kvx : qx;
    const bf16* w1 = wbf + (mode ? 1 : 0) * 16384;  // w_k : w_q
    const bf16* w2 = wbf + (mode ? 2 : 3) * 16384;  // w_v : w_g
    bf16* o1 = mode ? ko : qo;
    bf16* o2 = mode ? vo : go;

    {
        const float4* src = (const float4*)(x + (size_t)m0 * CQ);
        #pragma unroll
        for (int it = 0; it < 8; it++) {
            int i = t + it * 256;
            float4 v = src[i];
            int row = (i * 4) >> 7, col = (i * 4) & 127;
            bf16x4 b = {(bf16)v.x, (bf16)v.y, (bf16)v.z, (bf16)v.w};
            *(bf16x4*)&xs[row][col] = b;
        }
    }
    __syncthreads();

    const int w = t >> 6, l = t & 63, lr = l & 15, lg = l >> 4;

    bf16x8 a[4];
    #pragma unroll
    for (int ks = 0; ks < 4; ks++)
        a[ks] = *(const bf16x8*)&xs[w * 16 + lr][ks * 32 + lg * 8];

    f32x4 acc1[8], acc2[8];
    #pragma unroll
    for (int nt = 0; nt < 8; nt++) { acc1[nt] = (f32x4)0.f; acc2[nt] = (f32x4)0.f; }

    #pragma unroll
    for (int nt = 0; nt < 8; nt++) {
        #pragma unroll
        for (int ks = 0; ks < 4; ks++) {
            bf16x8 b1 = *(const bf16x8*)&w1[(size_t)(nt * 16 + lr) * CQ + ks * 32 + lg * 8];
            acc1[nt] = MFMA16(a[ks], b1, acc1[nt]);
        }
        #pragma unroll
        for (int ks = 0; ks < 4; ks++) {
            bf16x8 b2 = *(const bf16x8*)&w2[(size_t)(nt * 16 + lr) * CQ + ks * 32 + lg * 8];
            acc2[nt] = MFMA16(a[ks], b2, acc2[nt]);
        }
    }

    const float qscale = 0.17677669529663687f * LOG2E;  // 1/sqrt(32) * log2e
    #pragma unroll
    for (int nt = 0; nt < 8; nt++) {
        #pragma unroll
        for (int r = 0; r < 4; r++) {
            int row = m0 + w * 16 + lg * 4 + r;
            int col = nt * 16 + lr;
            float v1 = acc1[nt][r], v2 = acc2[nt][r];
            if (mode == 0) {
                v1 *= qscale;
                v2 = __builtin_amdgcn_rcpf(1.f + __builtin_amdgcn_exp2f(-v2 * LOG2E));
            }
            o1[(size_t)row * HC + col] = (bf16)v1;
            o2[(size_t)row * HC + col] = (bf16)v2;
        }
    }
}

// ---------------------------------------------------------------------------
// Attention per (n1, h): all 256 q rows (64 per wave), 256 k, C=32.
// scores in log2 domain (log2e pre-folded into q and biases); softmax via
// exp2; PV with V^T held in XOR-swizzled LDS (conflict-free both sides).
// ---------------------------------------------------------------------------
__global__ __launch_bounds__(256, 3) void attn_kernel(const bf16* __restrict__ qw,
                                                      const bf16* __restrict__ kw,
                                                      const bf16* __restrict__ vw,
                                                      const bf16* __restrict__ gw,
                                                      const float* __restrict__ pair_bias,
                                                      const float* __restrict__ mask_bias,
                                                      bf16* __restrict__ ow) {
    const int n1 = blockIdx.x;
    const int h = blockIdx.y;

    __shared__ bf16 klds[256][40];   // stride 20 dw: conflict-free b128 reads
    __shared__ bf16 vts[32][256];    // V^T, col = k ^ 16*((c>>3)&3) ^ 8*(c&7)
    __shared__ bf16 ps[4][16][136];  // per-wave P tile, written in 128-k halves

    const int t = threadIdx.x;

    // stage K (row-major head slice) and V^T (swizzled) for this n1
    {
        const size_t base = ((size_t)n1 * NSEQ) * HC + (size_t)h * C;
        const int rr = t >> 2, cc4 = t & 3, ch = cc4 * 8;
        #pragma unroll
        for (int p = 0; p < 4; p++) {
            int row = p * 64 + rr;
            bf16x8 kv = *(const bf16x8*)&kw[base + (size_t)row * HC + ch];
            *(bf16x8*)&klds[row][ch] = kv;
            bf16x8 vv = *(const bf16x8*)&vw[base + (size_t)row * HC + ch];
            #pragma unroll
            for (int j = 0; j < 8; j++) {
                int colw = row ^ (cc4 << 4) ^ (j << 3);
                vts[ch + j][colw] = vv[j];
            }
        }
    }

    const int w = t >> 6, l = t & 63, lr = l & 15, lg = l >> 4;

    // mask_bias row for this n1, pre-scaled by log2e, held in registers
    float mbr[16];
    {
        const float* mb = mask_bias + (size_t)n1 * NSEQ;
        #pragma unroll
        for (int kt = 0; kt < 16; kt++) mbr[kt] = mb[kt * 16 + lr] * LOG2E;
    }
    const float* pb = pair_bias + (size_t)h * NSEQ * NSEQ;

    __syncthreads();

    for (int qt = 0; qt < 4; qt++) {
        const int q0 = w * 64 + qt * 16;

        bf16x8 qf = *(const bf16x8*)&qw[((size_t)(n1 * NSEQ + q0 + lr)) * HC + h * C + lg * 8];

        // init scores with biases (log2 domain), then accumulate QK^T
        f32x4 s[16];
        #pragma unroll
        for (int kt = 0; kt < 16; kt++) {
            #pragma unroll
            for (int r = 0; r < 4; r++)
                s[kt][r] = fmaf(pb[(size_t)(q0 + lg * 4 + r) * NSEQ + kt * 16 + lr],
                                LOG2E, mbr[kt]);
        }
        #pragma unroll
        for (int kt = 0; kt < 16; kt++) {
            bf16x8 kf = *(const bf16x8*)&klds[kt * 16 + lr][lg * 8];
            s[kt] = MFMA16(qf, kf, s[kt]);
        }

        // softmax per q-row (16 lanes of the lg-group hold all 256 k)
        float pinv[4];
        #pragma unroll
        for (int r = 0; r < 4; r++) {
            float mx = s[0][r];
            #pragma unroll
            for (int kt = 1; kt < 16; kt++) mx = fmaxf(mx, s[kt][r]);
            #pragma unroll
            for (int msk = 8; msk >= 1; msk >>= 1) mx = fmaxf(mx, __shfl_xor(mx, msk, 64));
            float sum = 0.f;
            #pragma unroll
            for (int kt = 0; kt < 16; kt++) {
                float e = __builtin_amdgcn_exp2f(s[kt][r] - mx);
                s[kt][r] = e;
                sum += e;
            }
            #pragma unroll
            for (int msk = 8; msk >= 1; msk >>= 1) sum += __shfl_xor(sum, msk, 64);
            pinv[r] = __builtin_amdgcn_rcpf(sum);
        }

        // PV in two 128-k halves: write P half -> MFMA half (same-wave LDS,
        // in-order, no barrier needed; ps is per-wave)
        f32x4 o[2];
        o[0] = (f32x4)0.f;
        o[1] = (f32x4)0.f;
        #pragma unroll
        for (int hf = 0; hf < 2; hf++) {
            #pragma unroll
            for (int kt2 = 0; kt2 < 8; kt2++) {
                #pragma unroll
                for (int r = 0; r < 4; r++)
                    ps[w][lg * 4 + r][kt2 * 16 + lr] = (bf16)(s[hf * 8 + kt2][r] * pinv[r]);
            }
            #pragma unroll
            for (int kh = 0; kh < 4; kh++) {
                bf16x8 pf = *(const bf16x8*)&ps[w][lr][kh * 32 + lg * 8];
                #pragma unroll
                for (int ct = 0; ct < 2; ct++) {
                    int g2 = (2 * ct + (lr >> 3)) & 3;
                    int col0 = (hf * 128 + kh * 32 + lg * 8) ^ (g2 << 4) ^ ((lr & 7) << 3);
                    bf16x8 vf = *(const bf16x8*)&vts[ct * 16 + lr][col0];
                    o[ct] = MFMA16(pf, vf, o[ct]);
                }
            }
        }

        // gate + store head slice
        #pragma unroll
        for (int ct = 0; ct < 2; ct++) {
            #pragma unroll
            for (int r = 0; r < 4; r++) {
                size_t idx = ((size_t)(n1 * NSEQ + q0 + lg * 4 + r)) * HC + (size_t)h * C +
                             ct * 16 + lr;
                float gv = (float)gw[idx];
                ow[idx] = (bf16)(o[ct][r] * gv);
            }
        }
    }
}

// ---------------------------------------------------------------------------
// Output projection: out[m, c] = sum_d og[m, d] * w_o[c, d]  (f32 out)
// og-tile staged in LDS; w_o fragments from global bf16.
// ---------------------------------------------------------------------------
__global__ __launch_bounds__(256, 3) void out_proj(const bf16* __restrict__ og,
                                                   const bf16* __restrict__ wo,
                                                   float* __restrict__ out) {
    __shared__ bf16 xs[64][136];
    const int t = threadIdx.x;
    const int m0 = blockIdx.x * 64;

    const bf16x8* src = (const bf16x8*)(og + (size_t)m0 * HC);
    #pragma unroll
    for (int it = 0; it < 4; it++) {
        int i = t + it * 256;
        bf16x8 v = src[i];
        int row = (i * 8) >> 7, col = (i * 8) & 127;
        *(bf16x8*)&xs[row][col] = v;
    }
    __syncthreads();

    const int w = t >> 6, l = t & 63, lr = l & 15, lg = l >> 4;
    bf16x8 a[4];
    #pragma unroll
    for (int ks = 0; ks < 4; ks++)
        a[ks] = *(const bf16x8*)&xs[w * 16 + lr][ks * 32 + lg * 8];

    f32x4 acc[8];
    #pragma unroll
    for (int nt = 0; nt < 8; nt++) acc[nt] = (f32x4)0.f;
    #pragma unroll
    for (int nt = 0; nt < 8; nt++) {
        #pragma unroll
        for (int ks = 0; ks < 4; ks++) {
            bf16x8 b = *(const bf16x8*)&wo[(size_t)(nt * 16 + lr) * CQ + ks * 32 + lg * 8];
            acc[nt] = MFMA16(a[ks], b, acc[nt]);
        }
    }

    #pragma unroll
    for (int nt = 0; nt < 8; nt++)
        #pragma unroll
        for (int r = 0; r < 4; r++)
            out[(size_t)(m0 + w * 16 + lg * 4 + r) * CQ + nt * 16 + lr] = acc[nt][r];
}

// ---------------------------------------------------------------------------
extern "C" void kernel_launch(void* const* d_in, const int* in_sizes, int n_in,
                              void* d_out, int out_size, void* d_ws, size_t ws_size,
                              hipStream_t stream) {
    const float* q_x = (const float*)d_in[0];
    const float* kv_x = (const float*)d_in[1];
    const float* mask_bias = (const float*)d_in[2];
    const float* pair_bias = (const float*)d_in[3];
    const float* w_q = (const float*)d_in[4];
    const float* w_k = (const float*)d_in[5];
    const float* w_v = (const float*)d_in[6];
    const float* w_g = (const float*)d_in[7];
    const float* w_o = (const float*)d_in[8];

    const size_t M = (size_t)NSEQ * NSEQ;  // 65536
    bf16* wbf = (bf16*)d_ws;               // [5][16384] bf16: q,k,v,g,o
    bf16* qws = wbf + 5 * 16384;
    bf16* gws = qws + M * HC;
    bf16* kws = gws + M * HC;
    bf16* vws = kws + M * HC;
    bf16* ows = vws + M * HC;

    prep_weights<<<dim3(16, 5), 256, 0, stream>>>(w_q, w_k, w_v, w_g, w_o, wbf);
    proj_all<<<dim3(1024, 2), 256, 0, stream>>>(q_x, kv_x, wbf, qws, gws, kws, vws);
    attn_kernel<<<dim3(256, 4), 256, 0, stream>>>(qws, kws, vws, gws, pair_bias,
                                                  mask_bias, ows);
    out_proj<<<dim3(1024), 256, 0, stream>>>(ows, wbf + 4 * 16384, (float*)d_out);
}

// Round 3
// 151.851 us; speedup vs baseline: 2.0229x; 2.0229x over previous
//
#include <hip/hip_runtime.h>
#include <hip/hip_bf16.h>

#define H 4
#define C 32
#define CQ 128
#define NSEQ 256
#define HC 128   // H*C

typedef __bf16 bf16;
typedef __bf16 bf16x8 __attribute__((ext_vector_type(8)));
typedef __bf16 bf16x4 __attribute__((ext_vector_type(4)));
typedef float f32x4 __attribute__((ext_vector_type(4)));

#define MFMA16(a, b, c) __builtin_amdgcn_mfma_f32_16x16x32_bf16(a, b, c, 0, 0, 0)

#define LOG2E 1.4426950408889634f

// ---------------------------------------------------------------------------
// Convert the 5 weight matrices (each 128x128 f32) to bf16 in ws.
// ---------------------------------------------------------------------------
__global__ __launch_bounds__(256) void prep_weights(const float* __restrict__ wq,
                                                    const float* __restrict__ wk,
                                                    const float* __restrict__ wv,
                                                    const float* __restrict__ wg,
                                                    const float* __restrict__ wo,
                                                    bf16* __restrict__ dst) {
    const int m = blockIdx.y;
    const float* src = (m == 0) ? wq : (m == 1) ? wk : (m == 2) ? wv : (m == 3) ? wg : wo;
    int i = blockIdx.x * 256 + threadIdx.x;  // 4096 float4's per matrix
    float4 v = ((const float4*)src)[i];
    bf16x4 b = {(bf16)v.x, (bf16)v.y, (bf16)v.z, (bf16)v.w};
    ((bf16x4*)(dst + (size_t)m * 16384))[i] = b;
}

// ---------------------------------------------------------------------------
// Dual projection, both input streams in one dispatch (blockIdx.y = mode).
// mode 0: q = (q_x @ w_q^T) * (1/sqrt(32)*log2e),  g = sigmoid(q_x @ w_g^T)
// mode 1: k = kv_x @ w_k^T,  v = kv_x @ w_v^T
// x-tile (64 rows) staged in LDS; weight fragments read from global bf16.
// ---------------------------------------------------------------------------
__global__ __launch_bounds__(256) void proj_all(const float* __restrict__ qx,
                                                const float* __restrict__ kvx,
                                                const bf16* __restrict__ wbf,
                                                bf16* __restrict__ qo,
                                                bf16* __restrict__ go,
                                                bf16* __restrict__ ko,
                                                bf16* __restrict__ vo) {
    __shared__ bf16 xs[64][136];
    const int t = threadIdx.x;
    const int mode = blockIdx.y;
    const int m0 = blockIdx.x * 64;

    const float* x = mode ? kvx : qx;
    const bf16* w1 = wbf + (mode ? 1 : 0) * 16384;  // w_k : w_q
    const bf16* w2 = wbf + (mode ? 2 : 3) * 16384;  // w_v : w_g
    bf16* o1 = mode ? ko : qo;
    bf16* o2 = mode ? vo : go;

    {
        const float4* src = (const float4*)(x + (size_t)m0 * CQ);
        #pragma unroll
        for (int it = 0; it < 8; it++) {
            int i = t + it * 256;
            float4 v = src[i];
            int row = (i * 4) >> 7, col = (i * 4) & 127;
            bf16x4 b = {(bf16)v.x, (bf16)v.y, (bf16)v.z, (bf16)v.w};
            *(bf16x4*)&xs[row][col] = b;
        }
    }
    __syncthreads();

    const int w = t >> 6, l = t & 63, lr = l & 15, lg = l >> 4;

    bf16x8 a[4];
    #pragma unroll
    for (int ks = 0; ks < 4; ks++)
        a[ks] = *(const bf16x8*)&xs[w * 16 + lr][ks * 32 + lg * 8];

    f32x4 acc1[8], acc2[8];
    #pragma unroll
    for (int nt = 0; nt < 8; nt++) { acc1[nt] = (f32x4)0.f; acc2[nt] = (f32x4)0.f; }

    #pragma unroll
    for (int nt = 0; nt < 8; nt++) {
        #pragma unroll
        for (int ks = 0; ks < 4; ks++) {
            bf16x8 b1 = *(const bf16x8*)&w1[(size_t)(nt * 16 + lr) * CQ + ks * 32 + lg * 8];
            acc1[nt] = MFMA16(a[ks], b1, acc1[nt]);
        }
        #pragma unroll
        for (int ks = 0; ks < 4; ks++) {
            bf16x8 b2 = *(const bf16x8*)&w2[(size_t)(nt * 16 + lr) * CQ + ks * 32 + lg * 8];
            acc2[nt] = MFMA16(a[ks], b2, acc2[nt]);
        }
    }

    const float qscale = 0.17677669529663687f * LOG2E;  // 1/sqrt(32) * log2e
    #pragma unroll
    for (int nt = 0; nt < 8; nt++) {
        #pragma unroll
        for (int r = 0; r < 4; r++) {
            int row = m0 + w * 16 + lg * 4 + r;
            int col = nt * 16 + lr;
            float v1 = acc1[nt][r], v2 = acc2[nt][r];
            if (mode == 0) {
                v1 *= qscale;
                v2 = __builtin_amdgcn_rcpf(1.f + __builtin_amdgcn_exp2f(-v2 * LOG2E));
            }
            o1[(size_t)row * HC + col] = (bf16)v1;
            o2[(size_t)row * HC + col] = (bf16)v2;
        }
    }
}

// ---------------------------------------------------------------------------
// Attention per (qc, n1, h): 64 q-rows x 256 k, C=32. Linear 4096-block grid
// with chunked XCD swizzle so the 4 qc-blocks of one (n1,h) land on the SAME
// XCD (K/V fetched once per XCD; pair_bias slice L2-resident per XCD).
// Scores in log2 domain; softmax via exp2; PV in two 128-k halves through a
// small per-wave P tile (stride 132 -> conflict-free writes).
// ---------------------------------------------------------------------------
__global__ __launch_bounds__(256) void attn_kernel(const bf16* __restrict__ qw,
                                                   const bf16* __restrict__ kw,
                                                   const bf16* __restrict__ vw,
                                                   const bf16* __restrict__ gw,
                                                   const float* __restrict__ pair_bias,
                                                   const float* __restrict__ mask_bias,
                                                   bf16* __restrict__ ow) {
    // chunked XCD swizzle: hw-id wg -> work-id swz; XCD k owns swz [512k,512k+512)
    const int wg = blockIdx.x;
    const int swz = ((wg & 7) << 9) + (wg >> 3);
    const int qc = swz & 3;
    const int n1 = (swz >> 2) & 255;
    const int h = swz >> 10;

    __shared__ bf16 klds[256][40];   // K slice [k][c], stride 20 dw
    __shared__ bf16 vts[32][256];    // V^T, col = k ^ 16*((c>>3)&3) ^ 8*(c&7)
    __shared__ bf16 ps[4][16][132];  // per-wave P tile, 128-k halves, stride 66 dw

    const int t = threadIdx.x;

    // stage K (row-major head slice) and V^T (swizzled) for this n1
    {
        const size_t base = ((size_t)n1 * NSEQ) * HC + (size_t)h * C;
        const int rr = t >> 2, cc4 = t & 3, ch = cc4 * 8;
        #pragma unroll
        for (int p = 0; p < 4; p++) {
            int row = p * 64 + rr;
            bf16x8 kv = *(const bf16x8*)&kw[base + (size_t)row * HC + ch];
            *(bf16x8*)&klds[row][ch] = kv;
            bf16x8 vv = *(const bf16x8*)&vw[base + (size_t)row * HC + ch];
            #pragma unroll
            for (int j = 0; j < 8; j++) {
                int colw = row ^ (cc4 << 4) ^ (j << 3);
                vts[ch + j][colw] = vv[j];
            }
        }
    }

    const int w = t >> 6, l = t & 63, lr = l & 15, lg = l >> 4;
    const int qbase = qc * 64 + w * 16;

    // Q fragment: A[q=lr][c = lg*8 + j]  (log2e pre-folded at projection)
    bf16x8 qf = *(const bf16x8*)&qw[((size_t)(n1 * NSEQ + qbase + lr)) * HC + h * C + lg * 8];

    const float* pb = pair_bias + (size_t)h * NSEQ * NSEQ;
    const float* mb = mask_bias + (size_t)n1 * NSEQ;

    __syncthreads();

    // init scores with biases (log2 domain), then accumulate QK^T
    f32x4 s[16];
    #pragma unroll
    for (int kt = 0; kt < 16; kt++) {
        float mbk = mb[kt * 16 + lr] * LOG2E;
        #pragma unroll
        for (int r = 0; r < 4; r++)
            s[kt][r] = fmaf(pb[(size_t)(qbase + lg * 4 + r) * NSEQ + kt * 16 + lr],
                            LOG2E, mbk);
    }
    #pragma unroll
    for (int kt = 0; kt < 16; kt++) {
        bf16x8 kf = *(const bf16x8*)&klds[kt * 16 + lr][lg * 8];
        s[kt] = MFMA16(qf, kf, s[kt]);
    }

    // softmax per q-row (16 lanes of the lg-group hold all 256 k)
    float pinv[4];
    #pragma unroll
    for (int r = 0; r < 4; r++) {
        float mx = s[0][r];
        #pragma unroll
        for (int kt = 1; kt < 16; kt++) mx = fmaxf(mx, s[kt][r]);
        #pragma unroll
        for (int msk = 8; msk >= 1; msk >>= 1) mx = fmaxf(mx, __shfl_xor(mx, msk, 64));
        float sum = 0.f;
        #pragma unroll
        for (int kt = 0; kt < 16; kt++) {
            float e = __builtin_amdgcn_exp2f(s[kt][r] - mx);
            s[kt][r] = e;
            sum += e;
        }
        #pragma unroll
        for (int msk = 8; msk >= 1; msk >>= 1) sum += __shfl_xor(sum, msk, 64);
        pinv[r] = __builtin_amdgcn_rcpf(sum);
    }

    // PV in two 128-k halves: write P half -> MFMA half (same-wave LDS,
    // in-order; ps is per-wave so no barrier)
    f32x4 o[2];
    o[0] = (f32x4)0.f;
    o[1] = (f32x4)0.f;
    #pragma unroll
    for (int hf = 0; hf < 2; hf++) {
        #pragma unroll
        for (int kt2 = 0; kt2 < 8; kt2++) {
            #pragma unroll
            for (int r = 0; r < 4; r++)
                ps[w][lg * 4 + r][kt2 * 16 + lr] = (bf16)(s[hf * 8 + kt2][r] * pinv[r]);
        }
        #pragma unroll
        for (int kh = 0; kh < 4; kh++) {
            bf16x8 pf = *(const bf16x8*)&ps[w][lr][kh * 32 + lg * 8];
            #pragma unroll
            for (int ct = 0; ct < 2; ct++) {
                int g2 = (2 * ct + (lr >> 3)) & 3;
                int col0 = (hf * 128 + kh * 32 + lg * 8) ^ (g2 << 4) ^ ((lr & 7) << 3);
                bf16x8 vf = *(const bf16x8*)&vts[ct * 16 + lr][col0];
                o[ct] = MFMA16(pf, vf, o[ct]);
            }
        }
    }

    // gate + store head slice
    #pragma unroll
    for (int ct = 0; ct < 2; ct++) {
        #pragma unroll
        for (int r = 0; r < 4; r++) {
            size_t idx = ((size_t)(n1 * NSEQ + qbase + lg * 4 + r)) * HC + (size_t)h * C +
                         ct * 16 + lr;
            float gv = (float)gw[idx];
            ow[idx] = (bf16)(o[ct][r] * gv);
        }
    }
}

// ---------------------------------------------------------------------------
// Output projection: out[m, c] = sum_d og[m, d] * w_o[c, d]  (f32 out)
// ---------------------------------------------------------------------------
__global__ __launch_bounds__(256) void out_proj(const bf16* __restrict__ og,
                                                const bf16* __restrict__ wo,
                                                float* __restrict__ out) {
    __shared__ bf16 xs[64][136];
    const int t = threadIdx.x;
    const int m0 = blockIdx.x * 64;

    const bf16x8* src = (const bf16x8*)(og + (size_t)m0 * HC);
    #pragma unroll
    for (int it = 0; it < 4; it++) {
        int i = t + it * 256;
        bf16x8 v = src[i];
        int row = (i * 8) >> 7, col = (i * 8) & 127;
        *(bf16x8*)&xs[row][col] = v;
    }
    __syncthreads();

    const int w = t >> 6, l = t & 63, lr = l & 15, lg = l >> 4;
    bf16x8 a[4];
    #pragma unroll
    for (int ks = 0; ks < 4; ks++)
        a[ks] = *(const bf16x8*)&xs[w * 16 + lr][ks * 32 + lg * 8];

    f32x4 acc[8];
    #pragma unroll
    for (int nt = 0; nt < 8; nt++) acc[nt] = (f32x4)0.f;
    #pragma unroll
    for (int nt = 0; nt < 8; nt++) {
        #pragma unroll
        for (int ks = 0; ks < 4; ks++) {
            bf16x8 b = *(const bf16x8*)&wo[(size_t)(nt * 16 + lr) * CQ + ks * 32 + lg * 8];
            acc[nt] = MFMA16(a[ks], b, acc[nt]);
        }
    }

    #pragma unroll
    for (int nt = 0; nt < 8; nt++)
        #pragma unroll
        for (int r = 0; r < 4; r++)
            out[(size_t)(m0 + w * 16 + lg * 4 + r) * CQ + nt * 16 + lr] = acc[nt][r];
}

// ---------------------------------------------------------------------------
extern "C" void kernel_launch(void* const* d_in, const int* in_sizes, int n_in,
                              void* d_out, int out_size, void* d_ws, size_t ws_size,
                              hipStream_t stream) {
    const float* q_x = (const float*)d_in[0];
    const float* kv_x = (const float*)d_in[1];
    const float* mask_bias = (const float*)d_in[2];
    const float* pair_bias = (const float*)d_in[3];
    const float* w_q = (const float*)d_in[4];
    const float* w_k = (const float*)d_in[5];
    const float* w_v = (const float*)d_in[6];
    const float* w_g = (const float*)d_in[7];
    const float* w_o = (const float*)d_in[8];

    const size_t M = (size_t)NSEQ * NSEQ;  // 65536
    bf16* wbf = (bf16*)d_ws;               // [5][16384] bf16: q,k,v,g,o
    bf16* qws = wbf + 5 * 16384;
    bf16* gws = qws + M * HC;
    bf16* kws = gws + M * HC;
    bf16* vws = kws + M * HC;
    bf16* ows = vws + M * HC;

    prep_weights<<<dim3(16, 5), 256, 0, stream>>>(w_q, w_k, w_v, w_g, w_o, wbf);
    proj_all<<<dim3(1024, 2), 256, 0, stream>>>(q_x, kv_x, wbf, qws, gws, kws, vws);
    attn_kernel<<<dim3(4096), 256, 0, stream>>>(qws, kws, vws, gws, pair_bias,
                                                mask_bias, ows);
    out_proj<<<dim3(1024), 256, 0, stream>>>(ows, wbf + 4 * 16384, (float*)d_out);
}

// Round 4
// 105.210 us; speedup vs baseline: 2.9196x; 1.4433x over previous
//
#include <hip/hip_runtime.h>
#include <hip/hip_bf16.h>

#define H 4
#define C 32
#define CQ 128
#define NSEQ 256
#define HC 128   // H*C

typedef __bf16 bf16;
typedef __bf16 bf16x8 __attribute__((ext_vector_type(8)));
typedef __bf16 bf16x4 __attribute__((ext_vector_type(4)));
typedef float f32x4 __attribute__((ext_vector_type(4)));

#define MFMA16(a, b, c) __builtin_amdgcn_mfma_f32_16x16x32_bf16(a, b, c, 0, 0, 0)

#define LOG2E 1.4426950408889634f

// ---------------------------------------------------------------------------
// Convert the 5 weight matrices (each 128x128 f32) to bf16 in ws.
// ---------------------------------------------------------------------------
__global__ __launch_bounds__(256) void prep_weights(const float* __restrict__ wq,
                                                    const float* __restrict__ wk,
                                                    const float* __restrict__ wv,
                                                    const float* __restrict__ wg,
                                                    const float* __restrict__ wo,
                                                    bf16* __restrict__ dst) {
    const int m = blockIdx.y;
    const float* src = (m == 0) ? wq : (m == 1) ? wk : (m == 2) ? wv : (m == 3) ? wg : wo;
    int i = blockIdx.x * 256 + threadIdx.x;  // 4096 float4's per matrix
    float4 v = ((const float4*)src)[i];
    bf16x4 b = {(bf16)v.x, (bf16)v.y, (bf16)v.z, (bf16)v.w};
    ((bf16x4*)(dst + (size_t)m * 16384))[i] = b;
}

// ---------------------------------------------------------------------------
// Dual projection, register-resident weights, no LDS.
// blockIdx.y = mode. mode 0: q = (q_x@w_q^T)*(qscale*log2e), g = sigmoid(.@w_g^T)
//                    mode 1: k = kv_x@w_k^T, v = kv_x@w_v^T
// Block = 128 rows. Wave w owns output col-strips {2w,2w+1} of BOTH matrices;
// its 16 B-fragments (64 VGPR) are loaded once and reused for all 8 subtiles.
// A-fragments are read directly from global f32 (2x float4 + cvt).
// ---------------------------------------------------------------------------
__global__ __launch_bounds__(256) void proj_all(const float* __restrict__ qx,
                                                const float* __restrict__ kvx,
                                                const bf16* __restrict__ wbf,
                                                bf16* __restrict__ qo,
                                                bf16* __restrict__ go,
                                                bf16* __restrict__ ko,
                                                bf16* __restrict__ vo) {
    const int t = threadIdx.x;
    const int mode = blockIdx.y;
    const int m0 = blockIdx.x * 128;

    const float* x = mode ? kvx : qx;
    const bf16* w1 = wbf + (mode ? 1 : 0) * 16384;  // w_k : w_q
    const bf16* w2 = wbf + (mode ? 2 : 3) * 16384;  // w_v : w_g
    bf16* o1 = mode ? ko : qo;
    bf16* o2 = mode ? vo : go;

    const int w = t >> 6, l = t & 63, lr = l & 15, lg = l >> 4;

    // B fragments: strips nt = 2w, 2w+1 for both matrices (loaded once)
    bf16x8 b1[2][4], b2[2][4];
    #pragma unroll
    for (int i = 0; i < 2; i++) {
        const int ntr = (2 * w + i) * 16 + lr;
        #pragma unroll
        for (int ks = 0; ks < 4; ks++) {
            b1[i][ks] = *(const bf16x8*)&w1[(size_t)ntr * CQ + ks * 32 + lg * 8];
            b2[i][ks] = *(const bf16x8*)&w2[(size_t)ntr * CQ + ks * 32 + lg * 8];
        }
    }

    const float qscale = 0.17677669529663687f * LOG2E;  // 1/sqrt(32) * log2e

    for (int s = 0; s < 8; s++) {
        const int row0 = m0 + s * 16;

        bf16x8 a[4];
        #pragma unroll
        for (int ks = 0; ks < 4; ks++) {
            const float* p = x + (size_t)(row0 + lr) * CQ + ks * 32 + lg * 8;
            float4 lo = *(const float4*)p;
            float4 hi = *(const float4*)(p + 4);
            bf16x8 af = {(bf16)lo.x, (bf16)lo.y, (bf16)lo.z, (bf16)lo.w,
                         (bf16)hi.x, (bf16)hi.y, (bf16)hi.z, (bf16)hi.w};
            a[ks] = af;
        }

        f32x4 acc1[2], acc2[2];
        acc1[0] = (f32x4)0.f; acc1[1] = (f32x4)0.f;
        acc2[0] = (f32x4)0.f; acc2[1] = (f32x4)0.f;
        #pragma unroll
        for (int ks = 0; ks < 4; ks++) {
            acc1[0] = MFMA16(a[ks], b1[0][ks], acc1[0]);
            acc1[1] = MFMA16(a[ks], b1[1][ks], acc1[1]);
            acc2[0] = MFMA16(a[ks], b2[0][ks], acc2[0]);
            acc2[1] = MFMA16(a[ks], b2[1][ks], acc2[1]);
        }

        #pragma unroll
        for (int i = 0; i < 2; i++) {
            const int coln = (2 * w + i) * 16 + lr;
            #pragma unroll
            for (int r = 0; r < 4; r++) {
                const int row = row0 + lg * 4 + r;
                float v1 = acc1[i][r], v2 = acc2[i][r];
                if (mode == 0) {
                    v1 *= qscale;
                    v2 = __builtin_amdgcn_rcpf(1.f + __builtin_amdgcn_exp2f(-v2 * LOG2E));
                }
                o1[(size_t)row * HC + coln] = (bf16)v1;
                o2[(size_t)row * HC + coln] = (bf16)v2;
            }
        }
    }
}

// ---------------------------------------------------------------------------
// Attention per (qc, n1, h): 64 q-rows x 256 k, C=32. Linear 4096-block grid
// with chunked XCD swizzle so the 4 qc-blocks of one (n1,h) land on the SAME
// XCD. Scores in log2 domain; softmax via exp2; PV in two 128-k halves
// through a per-wave P tile.
// ---------------------------------------------------------------------------
__global__ __launch_bounds__(256) void attn_kernel(const bf16* __restrict__ qw,
                                                   const bf16* __restrict__ kw,
                                                   const bf16* __restrict__ vw,
                                                   const bf16* __restrict__ gw,
                                                   const float* __restrict__ pair_bias,
                                                   const float* __restrict__ mask_bias,
                                                   bf16* __restrict__ ow) {
    const int wg = blockIdx.x;
    const int swz = ((wg & 7) << 9) + (wg >> 3);
    const int qc = swz & 3;
    const int n1 = (swz >> 2) & 255;
    const int h = swz >> 10;

    __shared__ bf16 klds[256][40];   // K slice [k][c], stride 20 dw
    __shared__ bf16 vts[32][256];    // V^T, col = k ^ 16*((c>>3)&3) ^ 8*(c&7)
    __shared__ bf16 ps[4][16][132];  // per-wave P tile

    const int t = threadIdx.x;

    {
        const size_t base = ((size_t)n1 * NSEQ) * HC + (size_t)h * C;
        const int rr = t >> 2, cc4 = t & 3, ch = cc4 * 8;
        #pragma unroll
        for (int p = 0; p < 4; p++) {
            int row = p * 64 + rr;
            bf16x8 kv = *(const bf16x8*)&kw[base + (size_t)row * HC + ch];
            *(bf16x8*)&klds[row][ch] = kv;
            bf16x8 vv = *(const bf16x8*)&vw[base + (size_t)row * HC + ch];
            #pragma unroll
            for (int j = 0; j < 8; j++) {
                int colw = row ^ (cc4 << 4) ^ (j << 3);
                vts[ch + j][colw] = vv[j];
            }
        }
    }

    const int w = t >> 6, l = t & 63, lr = l & 15, lg = l >> 4;
    const int qbase = qc * 64 + w * 16;

    bf16x8 qf = *(const bf16x8*)&qw[((size_t)(n1 * NSEQ + qbase + lr)) * HC + h * C + lg * 8];

    const float* pb = pair_bias + (size_t)h * NSEQ * NSEQ;
    const float* mb = mask_bias + (size_t)n1 * NSEQ;

    __syncthreads();

    f32x4 s[16];
    #pragma unroll
    for (int kt = 0; kt < 16; kt++) {
        float mbk = mb[kt * 16 + lr] * LOG2E;
        #pragma unroll
        for (int r = 0; r < 4; r++)
            s[kt][r] = fmaf(pb[(size_t)(qbase + lg * 4 + r) * NSEQ + kt * 16 + lr],
                            LOG2E, mbk);
    }
    #pragma unroll
    for (int kt = 0; kt < 16; kt++) {
        bf16x8 kf = *(const bf16x8*)&klds[kt * 16 + lr][lg * 8];
        s[kt] = MFMA16(qf, kf, s[kt]);
    }

    float pinv[4];
    #pragma unroll
    for (int r = 0; r < 4; r++) {
        float mx = s[0][r];
        #pragma unroll
        for (int kt = 1; kt < 16; kt++) mx = fmaxf(mx, s[kt][r]);
        #pragma unroll
        for (int msk = 8; msk >= 1; msk >>= 1) mx = fmaxf(mx, __shfl_xor(mx, msk, 64));
        float sum = 0.f;
        #pragma unroll
        for (int kt = 0; kt < 16; kt++) {
            float e = __builtin_amdgcn_exp2f(s[kt][r] - mx);
            s[kt][r] = e;
            sum += e;
        }
        #pragma unroll
        for (int msk = 8; msk >= 1; msk >>= 1) sum += __shfl_xor(sum, msk, 64);
        pinv[r] = __builtin_amdgcn_rcpf(sum);
    }

    f32x4 o[2];
    o[0] = (f32x4)0.f;
    o[1] = (f32x4)0.f;
    #pragma unroll
    for (int hf = 0; hf < 2; hf++) {
        #pragma unroll
        for (int kt2 = 0; kt2 < 8; kt2++) {
            #pragma unroll
            for (int r = 0; r < 4; r++)
                ps[w][lg * 4 + r][kt2 * 16 + lr] = (bf16)(s[hf * 8 + kt2][r] * pinv[r]);
        }
        #pragma unroll
        for (int kh = 0; kh < 4; kh++) {
            bf16x8 pf = *(const bf16x8*)&ps[w][lr][kh * 32 + lg * 8];
            #pragma unroll
            for (int ct = 0; ct < 2; ct++) {
                int g2 = (2 * ct + (lr >> 3)) & 3;
                int col0 = (hf * 128 + kh * 32 + lg * 8) ^ (g2 << 4) ^ ((lr & 7) << 3);
                bf16x8 vf = *(const bf16x8*)&vts[ct * 16 + lr][col0];
                o[ct] = MFMA16(pf, vf, o[ct]);
            }
        }
    }

    #pragma unroll
    for (int ct = 0; ct < 2; ct++) {
        #pragma unroll
        for (int r = 0; r < 4; r++) {
            size_t idx = ((size_t)(n1 * NSEQ + qbase + lg * 4 + r)) * HC + (size_t)h * C +
                         ct * 16 + lr;
            float gv = (float)gw[idx];
            ow[idx] = (bf16)(o[ct][r] * gv);
        }
    }
}

// ---------------------------------------------------------------------------
// Output projection, register-resident w_o, no LDS.
// Block = 128 rows; wave w owns col-strips {2w, 2w+1}; 8 B-frags in regs.
// ---------------------------------------------------------------------------
__global__ __launch_bounds__(256) void out_proj(const bf16* __restrict__ og,
                                                const bf16* __restrict__ wo,
                                                float* __restrict__ out) {
    const int t = threadIdx.x;
    const int m0 = blockIdx.x * 128;
    const int w = t >> 6, l = t & 63, lr = l & 15, lg = l >> 4;

    bf16x8 b[2][4];
    #pragma unroll
    for (int i = 0; i < 2; i++) {
        const int ntr = (2 * w + i) * 16 + lr;
        #pragma unroll
        for (int ks = 0; ks < 4; ks++)
            b[i][ks] = *(const bf16x8*)&wo[(size_t)ntr * CQ + ks * 32 + lg * 8];
    }

    for (int s = 0; s < 8; s++) {
        const int row0 = m0 + s * 16;

        bf16x8 a[4];
        #pragma unroll
        for (int ks = 0; ks < 4; ks++)
            a[ks] = *(const bf16x8*)&og[(size_t)(row0 + lr) * HC + ks * 32 + lg * 8];

        f32x4 acc[2];
        acc[0] = (f32x4)0.f;
        acc[1] = (f32x4)0.f;
        #pragma unroll
        for (int ks = 0; ks < 4; ks++) {
            acc[0] = MFMA16(a[ks], b[0][ks], acc[0]);
            acc[1] = MFMA16(a[ks], b[1][ks], acc[1]);
        }

        #pragma unroll
        for (int i = 0; i < 2; i++) {
            const int coln = (2 * w + i) * 16 + lr;
            #pragma unroll
            for (int r = 0; r < 4; r++)
                out[(size_t)(row0 + lg * 4 + r) * CQ + coln] = acc[i][r];
        }
    }
}

// ---------------------------------------------------------------------------
extern "C" void kernel_launch(void* const* d_in, const int* in_sizes, int n_in,
                              void* d_out, int out_size, void* d_ws, size_t ws_size,
                              hipStream_t stream) {
    const float* q_x = (const float*)d_in[0];
    const float* kv_x = (const float*)d_in[1];
    const float* mask_bias = (const float*)d_in[2];
    const float* pair_bias = (const float*)d_in[3];
    const float* w_q = (const float*)d_in[4];
    const float* w_k = (const float*)d_in[5];
    const float* w_v = (const float*)d_in[6];
    const float* w_g = (const float*)d_in[7];
    const float* w_o = (const float*)d_in[8];

    const size_t M = (size_t)NSEQ * NSEQ;  // 65536
    bf16* wbf = (bf16*)d_ws;               // [5][16384] bf16: q,k,v,g,o
    bf16* qws = wbf + 5 * 16384;
    bf16* gws = qws + M * HC;
    bf16* kws = gws + M * HC;
    bf16* vws = kws + M * HC;
    bf16* ows = vws + M * HC;

    prep_weights<<<dim3(16, 5), 256, 0, stream>>>(w_q, w_k, w_v, w_g, w_o, wbf);
    proj_all<<<dim3(512, 2), 256, 0, stream>>>(q_x, kv_x, wbf, qws, gws, kws, vws);
    attn_kernel<<<dim3(4096), 256, 0, stream>>>(qws, kws, vws, gws, pair_bias,
                                                mask_bias, ows);
    out_proj<<<dim3(512), 256, 0, stream>>>(ows, wbf + 4 * 16384, (float*)d_out);
}